// Round 1
// baseline (500.560 us; speedup 1.0000x reference)
//
#include <hip/hip_runtime.h>
#include <hip/hip_bf16.h>
#include <math.h>

#define N_TOK 2048
#define DIM   1024
#define NE    16
#define NH    2048
#define NO    1024

typedef __attribute__((ext_vector_type(8))) short short8;
typedef __attribute__((ext_vector_type(4))) float f32x4;

__device__ __forceinline__ unsigned short f2bf(float f) {
  union { float f; unsigned u; } v; v.f = f;
  unsigned r = v.u + 0x7FFFu + ((v.u >> 16) & 1u);  // RNE
  return (unsigned short)(r >> 16);
}

__device__ __forceinline__ short8 pack8(float4 a, float4 b) {
  short8 r;
  r[0] = (short)f2bf(a.x); r[1] = (short)f2bf(a.y);
  r[2] = (short)f2bf(a.z); r[3] = (short)f2bf(a.w);
  r[4] = (short)f2bf(b.x); r[5] = (short)f2bf(b.y);
  r[6] = (short)f2bf(b.z); r[7] = (short)f2bf(b.w);
  return r;
}

__device__ __forceinline__ unsigned pkbf(float x, float y) {
  float2 f; f.x = x; f.y = y;
  __hip_bfloat162 b = __float22bfloat162_rn(f);     // v_cvt_pk_bf16_f32 (RNE)
  unsigned u; __builtin_memcpy(&u, &b, 4);
  return u;
}
__device__ __forceinline__ short8 cvt8(float4 a, float4 b) {
  union { short8 s; unsigned u[4]; } r;
  r.u[0] = pkbf(a.x, a.y); r.u[1] = pkbf(a.z, a.w);
  r.u[2] = pkbf(b.x, b.y); r.u[3] = pkbf(b.z, b.w);
  return r.s;
}

// async global->LDS, 16B/lane; LDS dest = wave-uniform base + lane*16 (m97/m104)
__device__ __forceinline__ void glds16(const void* g, void* l) {
  __builtin_amdgcn_global_load_lds(
      (const __attribute__((address_space(1))) void*)g,
      (__attribute__((address_space(3))) void*)l, 16, 0, 0);
}

// ---------------- Router: fp32 in, double accum, top-2 + renorm ----------------
__global__ __launch_bounds__(256) void router_kernel(
    const float* __restrict__ z, const float* __restrict__ rw,
    const float* __restrict__ rb, int* __restrict__ counts,
    int* __restrict__ list, float* __restrict__ tkw) {
  const int n = blockIdx.x;
  const int t = threadIdx.x;
  const int e = t >> 4, sub = t & 15;
  const float* zr = z + (size_t)n * DIM;
  const float* wr = rw + (size_t)e * DIM;
  double acc = 0.0;
#pragma unroll
  for (int i = 0; i < 16; ++i) {
    const int d = i * 64 + sub * 4;
    const float4 zv = *(const float4*)(zr + d);
    const float4 wv = *(const float4*)(wr + d);
    acc += (double)zv.x * wv.x + (double)zv.y * wv.y
         + (double)zv.z * wv.z + (double)zv.w * wv.w;
  }
  acc += __shfl_xor(acc, 8, 16);
  acc += __shfl_xor(acc, 4, 16);
  acc += __shfl_xor(acc, 2, 16);
  acc += __shfl_xor(acc, 1, 16);
  __shared__ double logits[NE];
  if (sub == 0) logits[e] = acc + (double)rb[e];
  __syncthreads();
  if (t == 0) {
    int i0 = -1, i1 = -1; double v0 = -1e300, v1 = -1e300;
    for (int i = 0; i < NE; ++i) {
      const double v = logits[i];
      if (v > v0) { v1 = v0; i1 = i0; v0 = v; i0 = i; }
      else if (v > v1) { v1 = v; i1 = i; }
    }
    const double w0 = 1.0 / (1.0 + exp(v1 - v0));
    tkw[n * 2 + 0] = (float)w0;
    tkw[n * 2 + 1] = (float)(1.0 - w0);
    const int p0 = atomicAdd(&counts[i0], 1); list[i0 * N_TOK + p0] = n * 2;
    const int p1 = atomicAdd(&counts[i1], 1); list[i1 * N_TOK + p1] = n * 2 + 1;
  }
}

// ---------------- z -> bf16 (once per call) ----------------
__global__ __launch_bounds__(256) void convert_z_kernel(
    const float* __restrict__ z, unsigned short* __restrict__ zbf) {
  const int i = (blockIdx.x * 256 + threadIdx.x) * 8;
  const float4 a = *(const float4*)(z + i);
  const float4 b = *(const float4*)(z + i + 4);
  *(short8*)(zbf + i) = pack8(a, b);
}

#define BM 128
#define BN 128
#define BK 64
#define NNT1 (NH / BN)   // 16
#define NNT2 (NO / BN)   // 8
#define MT_LEVELS 8
#define NT1 (DIM / BK)   // 16
#define NT2 (NH / BK)    // 32
#define ASZ (BM * BK * 2)  // 16 KB (bf16)
#define BSZ (BN * BK * 2)  // 16 KB (bf16)

// mt-major (active mt contiguous) + XCD-pair: the two mt blocks of one (e,nt)
// differ by bid 8 -> same XCD -> L2 merges the duplicate weight fetch.
__device__ __forceinline__ void decode_bid(int bid, int nent, int& mt, int& ent) {
  if (bid < 2 * nent) {
    mt = (bid >> 3) & 1;
    ent = (bid >> 4) * 8 + (bid & 7);
  } else {
    const int t2 = bid - 2 * nent;
    mt = 2 + t2 / nent;
    ent = t2 - (mt - 2) * nent;
  }
}

// ---------------- GEMM1: h[slot] = gelu(zbf[tok] @ w1[e]^T + b1[e]) -> bf16 ----------------
// 2-phase pipeline (T3-minimum): issue next-tile loads -> compute cur -> write B(next)
// -> one __syncthreads (its vmcnt(0) drain lands AFTER compute; loads overlap MFMA).
__global__ __launch_bounds__(256, 2) void gemm1_kernel(
    const unsigned short* __restrict__ zbf, const float* __restrict__ w1,
    const float* __restrict__ b1, const int* __restrict__ counts,
    const int* __restrict__ list, unsigned short* __restrict__ h) {
  int mt, ent;
  decode_bid(blockIdx.x, NE * NNT1, mt, ent);
  const int e  = ent >> 4;
  const int nt = ent & 15;
  const int ne = counts[e];
  if (mt * BM >= ne) return;
  const int t = threadIdx.x;

  __shared__ __align__(16) unsigned char As[2 * ASZ];   // 32 KB, double-buffered
  __shared__ __align__(16) unsigned char Bs[2 * BSZ];   // 32 KB, double-buffered (bf16!)
  __shared__ int ent_s[BM];
  if (t < BM) {
    const int idx = mt * BM + t;
    ent_s[t] = (idx < ne) ? list[e * N_TOK + idx] : -1;
  }
  __syncthreads();

  const int lane = t & 63, w = t >> 6;
  // ---- A staging: glds16 (linear LDS dest, pre-swizzled global source) ----
  const unsigned short* aP[4];
  unsigned char* aL[4];
  {
    const int l3 = lane >> 3, c7 = lane & 7;
#pragma unroll
    for (int p = 0; p < 4; ++p) {
      const int CI = w + 4 * p;
      const int R = 8 * CI + l3;
      const int c = c7 ^ (R & 7);
      const int en = ent_s[R];
      aP[p] = zbf + (size_t)(en >= 0 ? (en >> 1) : 0) * DIM + c * 8;
      aL[p] = As + CI * 1024;
    }
  }
  // ---- B staging: fp32 global -> regs -> cvt bf16 -> swizzled ds_write ----
  // lane covers half a row: row bR, floats [bh*32, bh*32+32) of the K-tile.
  const int bR = w * 32 + (lane >> 1);
  const int bh = lane & 1;
  const float* bSrc = w1 + ((size_t)e * NH + (size_t)(nt * BN + bR)) * DIM + bh * 32;
  unsigned char* bW[4];
#pragma unroll
  for (int j = 0; j < 4; ++j)
    bW[j] = Bs + bR * 128 + (((bh * 4 + j) ^ (bR & 7)) << 4);

  const int wm = (w & 1) * 64, wn = (w >> 1) * 64;
  const int l15 = lane & 15, quad = lane >> 4;

  f32x4 acc[4][4];
#pragma unroll
  for (int i = 0; i < 4; ++i)
#pragma unroll
    for (int j = 0; j < 4; ++j) acc[i][j] = (f32x4){0.f, 0.f, 0.f, 0.f};

  float4 breg[8];
  // prologue: tile 0 -> buffer 0
#pragma unroll
  for (int p = 0; p < 4; ++p) glds16(aP[p], aL[p]);
#pragma unroll
  for (int j = 0; j < 8; ++j) breg[j] = *(const float4*)(bSrc + j * 4);
#pragma unroll
  for (int j = 0; j < 4; ++j)
    *(short8*)(bW[j]) = cvt8(breg[2 * j], breg[2 * j + 1]);
  __syncthreads();

  for (int kt = 0; kt < NT1; ++kt) {
    const int cur = kt & 1, nxt = cur ^ 1;
    const int k1 = (kt + 1) * BK;
    if (kt + 1 < NT1) {            // issue next-tile loads BEFORE compute
#pragma unroll
      for (int p = 0; p < 4; ++p) glds16(aP[p] + k1, aL[p] + nxt * ASZ);
#pragma unroll
      for (int j = 0; j < 8; ++j) breg[j] = *(const float4*)(bSrc + k1 + j * 4);
    }
    const unsigned char* Ac = As + cur * ASZ;
    const unsigned char* Bc = Bs + cur * BSZ;
#pragma unroll
    for (int kk = 0; kk < BK; kk += 32) {
      short8 af[4], bfr[4];
      const int c0 = (kk >> 3) + quad;
#pragma unroll
      for (int i = 0; i < 4; ++i) {
        const int R = wm + i * 16 + l15;
        af[i] = *(const short8*)(Ac + R * 128 + ((c0 ^ (R & 7)) << 4));
      }
#pragma unroll
      for (int j = 0; j < 4; ++j) {
        const int R = wn + j * 16 + l15;
        bfr[j] = *(const short8*)(Bc + R * 128 + ((c0 ^ (R & 7)) << 4));
      }
#pragma unroll
      for (int i = 0; i < 4; ++i)
#pragma unroll
        for (int j = 0; j < 4; ++j)
          acc[i][j] = __builtin_amdgcn_mfma_f32_16x16x32_bf16(af[i], bfr[j], acc[i][j], 0, 0, 0);
    }
    if (kt + 1 < NT1) {            // cvt+write B(next) (waits its own vmem), then barrier
#pragma unroll
      for (int j = 0; j < 4; ++j)
        *(short8*)(bW[j] + nxt * BSZ) = cvt8(breg[2 * j], breg[2 * j + 1]);
      __syncthreads();             // drains glds16(next) too — overlapped with compute
    }
  }

  const int r4 = quad * 4;    // C/D: col=lane&15, row=quad*4+reg
#pragma unroll
  for (int i = 0; i < 4; ++i) {
#pragma unroll
    for (int reg = 0; reg < 4; ++reg) {
      const int row = wm + i * 16 + r4 + reg;
      const int en = ent_s[row];
      if (en < 0) continue;
      unsigned short* hrow = h + (size_t)en * NH;
#pragma unroll
      for (int j = 0; j < 4; ++j) {
        const int col = nt * BN + wn + j * 16 + l15;
        float v = acc[i][j][reg] + b1[e * NH + col];
        v = 0.5f * v * (1.0f + erff(v * 0.70710678118654752f));
        hrow[col] = f2bf(v);
      }
    }
  }
}

// ---------------- GEMM2: contrib[slot] = h[slot] @ w2[e]^T + b2[e] (fp32) ----------------
__global__ __launch_bounds__(256, 2) void gemm2_kernel(
    const unsigned short* __restrict__ h, const float* __restrict__ w2,
    const float* __restrict__ b2, const int* __restrict__ counts,
    const int* __restrict__ list, float* __restrict__ contrib) {
  int mt, ent;
  decode_bid(blockIdx.x, NE * NNT2, mt, ent);
  const int e  = ent >> 3;
  const int nt = ent & 7;
  const int ne = counts[e];
  if (mt * BM >= ne) return;
  const int t = threadIdx.x;

  __shared__ __align__(16) unsigned char As[2 * ASZ];
  __shared__ __align__(16) unsigned char Bs[2 * BSZ];
  __shared__ int ent_s[BM];
  if (t < BM) {
    const int idx = mt * BM + t;
    ent_s[t] = (idx < ne) ? list[e * N_TOK + idx] : -1;
  }
  __syncthreads();

  const int lane = t & 63, w = t >> 6;
  const unsigned short* aP[4];
  unsigned char* aL[4];
  {
    const int l3 = lane >> 3, c7 = lane & 7;
#pragma unroll
    for (int p = 0; p < 4; ++p) {
      const int CI = w + 4 * p;
      const int R = 8 * CI + l3;
      const int c = c7 ^ (R & 7);
      const int en = ent_s[R];
      aP[p] = h + (size_t)(en >= 0 ? en : 0) * NH + c * 8;
      aL[p] = As + CI * 1024;
    }
  }
  const int bR = w * 32 + (lane >> 1);
  const int bh = lane & 1;
  const float* bSrc = w2 + ((size_t)e * NO + (size_t)(nt * BN + bR)) * NH + bh * 32;
  unsigned char* bW[4];
#pragma unroll
  for (int j = 0; j < 4; ++j)
    bW[j] = Bs + bR * 128 + (((bh * 4 + j) ^ (bR & 7)) << 4);

  const int wm = (w & 1) * 64, wn = (w >> 1) * 64;
  const int l15 = lane & 15, quad = lane >> 4;

  f32x4 acc[4][4];
#pragma unroll
  for (int i = 0; i < 4; ++i)
#pragma unroll
    for (int j = 0; j < 4; ++j) acc[i][j] = (f32x4){0.f, 0.f, 0.f, 0.f};

  float4 breg[8];
#pragma unroll
  for (int p = 0; p < 4; ++p) glds16(aP[p], aL[p]);
#pragma unroll
  for (int j = 0; j < 8; ++j) breg[j] = *(const float4*)(bSrc + j * 4);
#pragma unroll
  for (int j = 0; j < 4; ++j)
    *(short8*)(bW[j]) = cvt8(breg[2 * j], breg[2 * j + 1]);
  __syncthreads();

  for (int kt = 0; kt < NT2; ++kt) {
    const int cur = kt & 1, nxt = cur ^ 1;
    const int k1 = (kt + 1) * BK;
    if (kt + 1 < NT2) {
#pragma unroll
      for (int p = 0; p < 4; ++p) glds16(aP[p] + k1, aL[p] + nxt * ASZ);
#pragma unroll
      for (int j = 0; j < 8; ++j) breg[j] = *(const float4*)(bSrc + k1 + j * 4);
    }
    const unsigned char* Ac = As + cur * ASZ;
    const unsigned char* Bc = Bs + cur * BSZ;
#pragma unroll
    for (int kk = 0; kk < BK; kk += 32) {
      short8 af[4], bfr[4];
      const int c0 = (kk >> 3) + quad;
#pragma unroll
      for (int i = 0; i < 4; ++i) {
        const int R = wm + i * 16 + l15;
        af[i] = *(const short8*)(Ac + R * 128 + ((c0 ^ (R & 7)) << 4));
      }
#pragma unroll
      for (int j = 0; j < 4; ++j) {
        const int R = wn + j * 16 + l15;
        bfr[j] = *(const short8*)(Bc + R * 128 + ((c0 ^ (R & 7)) << 4));
      }
#pragma unroll
      for (int i = 0; i < 4; ++i)
#pragma unroll
        for (int j = 0; j < 4; ++j)
          acc[i][j] = __builtin_amdgcn_mfma_f32_16x16x32_bf16(af[i], bfr[j], acc[i][j], 0, 0, 0);
    }
    if (kt + 1 < NT2) {
#pragma unroll
      for (int j = 0; j < 4; ++j)
        *(short8*)(bW[j] + nxt * BSZ) = cvt8(breg[2 * j], breg[2 * j + 1]);
      __syncthreads();
    }
  }

  const int r4 = quad * 4;
#pragma unroll
  for (int i = 0; i < 4; ++i) {
#pragma unroll
    for (int reg = 0; reg < 4; ++reg) {
      const int row = wm + i * 16 + r4 + reg;
      const int en = ent_s[row];
      if (en < 0) continue;
      float* crow = contrib + (size_t)en * NO;
#pragma unroll
      for (int j = 0; j < 4; ++j) {
        const int col = nt * BN + wn + j * 16 + l15;
        crow[col] = acc[i][j][reg] + b2[e * NO + col];
      }
    }
  }
}

// ---------------- Combine ----------------
__global__ __launch_bounds__(256) void combine_kernel(
    const float* __restrict__ contrib, const float* __restrict__ tkw,
    float* __restrict__ out) {
  const int gid = blockIdx.x * 256 + threadIdx.x;
  const int n = gid >> 8;
  const int c = (gid & 255) * 4;
  const float w0 = tkw[n * 2], w1 = tkw[n * 2 + 1];
  const float4 a = *(const float4*)(contrib + (size_t)(n * 2) * NO + c);
  const float4 b = *(const float4*)(contrib + (size_t)(n * 2 + 1) * NO + c);
  float4 o;
  o.x = w0 * a.x + w1 * b.x; o.y = w0 * a.y + w1 * b.y;
  o.z = w0 * a.z + w1 * b.z; o.w = w0 * a.w + w1 * b.w;
  *(float4*)(out + (size_t)n * NO + c) = o;
}

extern "C" void kernel_launch(void* const* d_in, const int* in_sizes, int n_in,
                              void* d_out, int out_size, void* d_ws, size_t ws_size,
                              hipStream_t stream) {
  const float* z  = (const float*)d_in[0];
  const float* rw = (const float*)d_in[1];
  const float* rb = (const float*)d_in[2];
  const float* w1 = (const float*)d_in[3];
  const float* b1 = (const float*)d_in[4];
  const float* w2 = (const float*)d_in[5];
  const float* b2 = (const float*)d_in[6];
  float* out = (float*)d_out;

  char* ws = (char*)d_ws;
  int*   counts = (int*)ws;                                    // 256 B
  int*   list   = (int*)(ws + 256);                            // 128 KB
  float* tkw    = (float*)(ws + 256 + 131072);                 // 16 KB
  unsigned short* zbf = (unsigned short*)(ws + 262144);        // 4 MB
  unsigned short* h = (unsigned short*)(ws + 262144 + 4194304);        // 16 MB
  float* contrib = (float*)(ws + 262144 + 4194304 + 16777216);         // 16 MB

  hipMemsetAsync(counts, 0, NE * sizeof(int), stream);
  convert_z_kernel<<<(N_TOK * DIM / 8) / 256, 256, 0, stream>>>(z, zbf);
  router_kernel<<<N_TOK, 256, 0, stream>>>(z, rw, rb, counts, list, tkw);
  gemm1_kernel<<<MT_LEVELS * NE * NNT1, 256, 0, stream>>>(zbf, w1, b1, counts, list, h);
  gemm2_kernel<<<MT_LEVELS * NE * NNT2, 256, 0, stream>>>(h, w2, b2, counts, list, contrib);
  combine_kernel<<<(N_TOK * (NO / 4)) / 256, 256, 0, stream>>>(contrib, tkw, out);
}